// Round 4
// baseline (159.633 us; speedup 1.0000x reference)
//
#include <hip/hip_runtime.h>
#include <math.h>

typedef float f32x4 __attribute__((ext_vector_type(4)));
typedef __bf16 bf16x8 __attribute__((ext_vector_type(8)));
typedef unsigned short u16x8 __attribute__((ext_vector_type(8)));
typedef unsigned short u16x4 __attribute__((ext_vector_type(4)));

#define DEV static __device__ __forceinline__

DEV unsigned short f2bf(float f) {
    unsigned int u = __builtin_bit_cast(unsigned int, f);
    u += 0x7fffu + ((u >> 16) & 1u);   // RNE
    return (unsigned short)(u >> 16);
}

// async global->LDS, 16B per lane; LDS dest is wave-uniform base + lane*16
#define GLD16(gp, lp) __builtin_amdgcn_global_load_lds( \
    (__attribute__((address_space(1))) void*)(gp),      \
    (__attribute__((address_space(3))) void*)(lp), 16, 0, 0)

// ---------------------------------------------------------------- cast x -> bf16
__global__ __launch_bounds__(256) void k_cast(const float* __restrict__ x,
                                              unsigned short* __restrict__ xb) {
    int i = blockIdx.x * 256 + threadIdx.x;
    const float4* p = (const float4*)(x + (size_t)i * 8);
    float4 a = p[0], b = p[1];
    u16x8 o;
    o[0] = f2bf(a.x); o[1] = f2bf(a.y); o[2] = f2bf(a.z); o[3] = f2bf(a.w);
    o[4] = f2bf(b.x); o[5] = f2bf(b.y); o[6] = f2bf(b.z); o[7] = f2bf(b.w);
    *(u16x8*)(xb + (size_t)i * 8) = o;
}

// ---------------- fused transpose+cast of wq,wk,wv: f32 [16 slices][1024][64]
// -> bf16 WqkvT rows [wsel*1024 + slice*64 + d][c]  (leading dim 1024)
__global__ __launch_bounds__(256) void k_transw3(const float* __restrict__ wq,
                                                 const float* __restrict__ wk,
                                                 const float* __restrict__ wv,
                                                 unsigned short* __restrict__ dst) {
    __shared__ unsigned short t[64][68];
    int z = blockIdx.z;          // 0..47
    int wsel = z >> 4, zz = z & 15;
    const float* src = (wsel == 0 ? wq : wsel == 1 ? wk : wv) + (size_t)zz * 65536;
    int r0 = blockIdx.x * 64;
    int tid = threadIdx.x;
#pragma unroll
    for (int it = 0; it < 4; ++it) {
        int r = (tid >> 4) + it * 16;
        int c4 = (tid & 15) * 4;
        float4 v = *(const float4*)&src[(size_t)(r0 + r) * 64 + c4];
        t[c4 + 0][r] = f2bf(v.x);
        t[c4 + 1][r] = f2bf(v.y);
        t[c4 + 2][r] = f2bf(v.z);
        t[c4 + 3][r] = f2bf(v.w);
    }
    __syncthreads();
#pragma unroll
    for (int it = 0; it < 4; ++it) {
        int c = (tid >> 4) + it * 16;
        int r4 = (tid & 15) * 4;
        u16x4 o;
        o[0] = t[c][r4 + 0]; o[1] = t[c][r4 + 1];
        o[2] = t[c][r4 + 2]; o[3] = t[c][r4 + 3];
        int row = wsel * 1024 + zz * 64 + c;
        *(u16x4*)&dst[(size_t)row * 1024 + r0 + r4] = o;
    }
}

// ------------------------------------------- transpose+cast f32 [R][C] -> bf16 [C][R]
__global__ __launch_bounds__(256) void k_transw(const float* __restrict__ src,
                                                unsigned short* __restrict__ dst,
                                                int Cdim) {
    __shared__ unsigned short t[64][68];
    int r0 = blockIdx.x * 64, c0 = blockIdx.y * 64;
    int tid = threadIdx.x;
#pragma unroll
    for (int it = 0; it < 4; ++it) {
        int r = (tid >> 4) + it * 16;
        int c4 = (tid & 15) * 4;
        float4 v = *(const float4*)&src[(size_t)(r0 + r) * Cdim + c0 + c4];
        t[c4 + 0][r] = f2bf(v.x);
        t[c4 + 1][r] = f2bf(v.y);
        t[c4 + 2][r] = f2bf(v.z);
        t[c4 + 3][r] = f2bf(v.w);
    }
    __syncthreads();
#pragma unroll
    for (int it = 0; it < 4; ++it) {
        int c = (tid >> 4) + it * 16;
        int r4 = (tid & 15) * 4;
        u16x4 o;
        o[0] = t[c][r4 + 0]; o[1] = t[c][r4 + 1];
        o[2] = t[c][r4 + 2]; o[3] = t[c][r4 + 3];
        *(u16x4*)&dst[(size_t)(c0 + c) * 1024 + r0 + r4] = o;
    }
}

// ---------------------------------------------------------------- GEMM  C = A * Bt^T
// 128x128 tile, BK=64, 4 waves, 2-phase double-buffered pipeline:
// issue STAGE(next K-tile) before compute(cur); single vmcnt(0)+barrier per tile.
// XCD-aware bijective swizzle: each XCD gets a contiguous bn chunk x all bm
// (B-panel chunk stays L2-resident; A-panel reused across neighboring bn).
// Grid is 1D: nwg = NB*32, bm blocks = 32 (M=4096).
template <int STAGE, int NB>
__global__ __launch_bounds__(256) void k_gemm(const unsigned short* __restrict__ A,
                                              const unsigned short* __restrict__ Bt,
                                              int Kd,
                                              float* __restrict__ outF,
                                              const float* __restrict__ bias,
                                              unsigned short* __restrict__ Qb,
                                              unsigned short* __restrict__ Kb,
                                              unsigned short* __restrict__ Vt) {
    __shared__ unsigned short As[2][128 * 64] __attribute__((aligned(16)));
    __shared__ unsigned short Bs[2][128 * 64] __attribute__((aligned(16)));
    const int tid = threadIdx.x, l = tid & 63, w = tid >> 6;
    const int orig = blockIdx.x;
    const int wg = (orig & 7) * (NB * 4) + (orig >> 3);  // bijective, nwg%8==0
    const int bn = wg >> 5, bm = wg & 31;
    const int wr = w >> 1, wc = w & 1;
    const int g = l >> 4, q = l & 15;
    f32x4 acc[4][4] = {};
    const unsigned short* gA = A + (size_t)(bm * 128 + w * 8 + (l >> 3)) * Kd + (l & 7) * 8;
    const unsigned short* gB = Bt + (size_t)(bn * 128 + w * 8 + (l >> 3)) * Kd + (l & 7) * 8;

#define GSTAGE(buf, k0) do {                                                  \
        _Pragma("unroll")                                                     \
        for (int it = 0; it < 4; ++it) {                                      \
            GLD16(gA + (size_t)(it * 32) * Kd + (k0), &As[buf][(it * 32 + w * 8) * 64]); \
            GLD16(gB + (size_t)(it * 32) * Kd + (k0), &Bs[buf][(it * 32 + w * 8) * 64]); \
        }                                                                     \
    } while (0)

    GSTAGE(0, 0);
    __syncthreads();  // drains vmcnt(0): buf0 staged
    int cur = 0;
    for (int k0 = 0; k0 < Kd; k0 += 64) {
        if (k0 + 64 < Kd) GSTAGE(cur ^ 1, k0 + 64);  // prefetch next tile (async)
        __builtin_amdgcn_sched_barrier(0);           // keep loads issued early
#pragma unroll
        for (int ks = 0; ks < 2; ++ks) {
            bf16x8 af[4], bfr[4];
#pragma unroll
            for (int mi = 0; mi < 4; ++mi)
                af[mi] = *(const bf16x8*)&As[cur][(wr * 64 + mi * 16 + q) * 64 + ks * 32 + g * 8];
#pragma unroll
            for (int ni = 0; ni < 4; ++ni)
                bfr[ni] = *(const bf16x8*)&Bs[cur][(wc * 64 + ni * 16 + q) * 64 + ks * 32 + g * 8];
#pragma unroll
            for (int mi = 0; mi < 4; ++mi)
#pragma unroll
                for (int ni = 0; ni < 4; ++ni)
                    acc[mi][ni] = __builtin_amdgcn_mfma_f32_16x16x32_bf16(
                        af[mi], bfr[ni], acc[mi][ni], 0, 0, 0);
        }
        __syncthreads();  // drains vmcnt(0)+lgkmcnt(0): prefetch landed, reads done
        cur ^= 1;
    }
#undef GSTAGE
#pragma unroll
    for (int mi = 0; mi < 4; ++mi)
#pragma unroll
        for (int ni = 0; ni < 4; ++ni)
#pragma unroll
            for (int r = 0; r < 4; ++r) {
                float c = acc[mi][ni][r];
                int m = bm * 128 + wr * 64 + mi * 16 + g * 4 + r;
                int n = bn * 128 + wc * 64 + ni * 16 + q;
                if (STAGE == 1) {
                    int b = m >> 11, t = m & 2047;
                    int proj = n >> 10, rr = n & 1023, h = rr >> 6, d = rr & 63;
                    int bh = b * 16 + h;
                    if (proj == 0)
                        Qb[((size_t)bh * 2048 + t) * 64 + d] = f2bf(c * 0.18033688011112042f);
                    else if (proj == 1)
                        Kb[((size_t)bh * 2048 + t) * 64 + d] = f2bf(c);
                    else
                        Vt[((size_t)bh * 64 + d) * 2048 + t] = f2bf(c);
                } else {
                    outF[(size_t)m * 1024 + n] = c + bias[n];
                }
            }
}

// ---------------------------------------------------------------- flash attention
// Cooperative: 8 waves/block, each wave owns 16 q-rows of a 128-row q-tile.
// K and V tiles (64x64 bf16) staged in LDS via global_load_lds, double-buffered,
// shared by all 8 waves. XOR pre-swizzle on the GLOBAL source (LDS stays linear).
// Causal balance: block processes q-tile pair (qt, 15-qt) -> exactly 34 KV-tile
// iterations per block; grid 8x32 = 256 blocks = 1 block/CU.
__global__ __launch_bounds__(512) void k_attn(const unsigned short* __restrict__ Qb,
                                              const unsigned short* __restrict__ Kb,
                                              const unsigned short* __restrict__ Vt,
                                              unsigned short* __restrict__ att) {
    __shared__ unsigned short Ks[2][4096] __attribute__((aligned(16)));  // [buf][64r][64]
    __shared__ unsigned short Vs[2][4096] __attribute__((aligned(16)));  // [buf][64d][64]
    __shared__ unsigned short P[8][16][72];  // per-wave P staging [q][kv], padded
    const int tid = threadIdx.x, l = tid & 63, w = tid >> 6;
    const int pj = blockIdx.x, bh = blockIdx.y;
    const int b = bh >> 4, h = bh & 15;
    const int ql = l & 15, g = l >> 4;
    const unsigned short* Qp = Qb + (size_t)bh * 2048 * 64;
    const unsigned short* Kp = Kb + (size_t)bh * 2048 * 64;
    const unsigned short* Vp = Vt + (size_t)bh * 64 * 2048;

    const int srow = w * 8 + (l >> 3);
    const int schk = (l & 7) ^ (l >> 3);
    const unsigned short* gK0 = Kp + (size_t)srow * 64 + schk * 8;
    const unsigned short* gV0 = Vp + (size_t)srow * 2048 + schk * 8;

#define ATT_STAGE(buf, kvb) do {                                   \
        GLD16(gK0 + (size_t)(kvb) * 64, &Ks[buf][w * 512]);        \
        GLD16(gV0 + (kvb), &Vs[buf][w * 512]);                     \
    } while (0)

    for (int ph = 0; ph < 2; ++ph) {
        const int qt = ph ? (15 - pj) : pj;
        const int q0w = qt * 128 + w * 16;
        const int qg = q0w + ql;
        const int nkv = 2 * qt + 2;
        const int kbd = 2 * qt + (w >> 2);  // this wave's diagonal tile index

        bf16x8 qf0 = *(const bf16x8*)(Qp + (size_t)qg * 64 + g * 8);
        bf16x8 qf1 = *(const bf16x8*)(Qp + (size_t)qg * 64 + 32 + g * 8);
        f32x4 ot[4] = {};
        float mrun = -1e30f, lrun = 0.f;

        ATT_STAGE(0, 0);
        asm volatile("s_waitcnt vmcnt(0)" ::: "memory");
        __syncthreads();
        int cur = 0;

        for (int kb = 0; kb < nkv; ++kb) {
            if (kb + 1 < nkv) ATT_STAGE(cur ^ 1, (kb + 1) * 64);  // prefetch next
            if (kb <= kbd) {
                const unsigned short* Kt = &Ks[cur][0];
                const unsigned short* Vtl = &Vs[cur][0];
                f32x4 st[4] = {};
                bf16x8 kf0[4], kf1[4];
#pragma unroll
                for (int f = 0; f < 4; ++f) {
                    int rk = f * 16 + ql, sw = rk & 7;
                    kf0[f] = *(const bf16x8*)&Kt[rk * 64 + ((g ^ sw) * 8)];
                    kf1[f] = *(const bf16x8*)&Kt[rk * 64 + (((g + 4) ^ sw) * 8)];
                }
                __builtin_amdgcn_s_setprio(1);
#pragma unroll
                for (int f = 0; f < 4; ++f) {
                    st[f] = __builtin_amdgcn_mfma_f32_16x16x32_bf16(kf0[f], qf0, st[f], 0, 0, 0);
                    st[f] = __builtin_amdgcn_mfma_f32_16x16x32_bf16(kf1[f], qf1, st[f], 0, 0, 0);
                }
                __builtin_amdgcn_s_setprio(0);
                if (kb == kbd) {  // diagonal tile: causal mask
                    const int kvb = kb * 64;
#pragma unroll
                    for (int f = 0; f < 4; ++f)
#pragma unroll
                        for (int r = 0; r < 4; ++r)
                            if (kvb + f * 16 + g * 4 + r > qg) st[f][r] = -1e30f;
                }
                float pmax = -1e30f;
#pragma unroll
                for (int f = 0; f < 4; ++f)
#pragma unroll
                    for (int r = 0; r < 4; ++r) pmax = fmaxf(pmax, st[f][r]);
                pmax = fmaxf(pmax, __shfl_xor(pmax, 16));
                pmax = fmaxf(pmax, __shfl_xor(pmax, 32));
                float mnew = fmaxf(mrun, pmax);
                float corr = __builtin_amdgcn_exp2f(mrun - mnew);
                float psum = 0.f;
#pragma unroll
                for (int f = 0; f < 4; ++f) {
                    u16x4 pk;
#pragma unroll
                    for (int r = 0; r < 4; ++r) {
                        float p = __builtin_amdgcn_exp2f(st[f][r] - mnew);
                        psum += p;
                        pk[r] = f2bf(p);
                    }
                    *(u16x4*)&P[w][ql][f * 16 + g * 4] = pk;  // b64 write
                }
                psum += __shfl_xor(psum, 16);
                psum += __shfl_xor(psum, 32);
                lrun = lrun * corr + psum;
#pragma unroll
                for (int f = 0; f < 4; ++f) ot[f] *= corr;
                mrun = mnew;
                asm volatile("s_waitcnt lgkmcnt(0)" ::: "memory");
#pragma unroll
                for (int dc = 0; dc < 2; ++dc) {
                    bf16x8 pf = *(const bf16x8*)&P[w][ql][dc * 32 + g * 8];  // b128 read
                    __builtin_amdgcn_s_setprio(1);
#pragma unroll
                    for (int f = 0; f < 4; ++f) {
                        int rv = f * 16 + ql, sw = rv & 7;
                        bf16x8 vf = *(const bf16x8*)&Vtl[rv * 64 + (((dc * 4 + g) ^ sw) * 8)];
                        ot[f] = __builtin_amdgcn_mfma_f32_16x16x32_bf16(vf, pf, ot[f], 0, 0, 0);
                    }
                    __builtin_amdgcn_s_setprio(0);
                }
            }
            asm volatile("s_waitcnt vmcnt(0)" ::: "memory");  // prefetch landed
            __syncthreads();
            cur ^= 1;
        }
        float inv = 1.f / lrun;
        unsigned short* ap = att + ((size_t)(b * 2048 + qg)) * 1024 + h * 64;
#pragma unroll
        for (int f = 0; f < 4; ++f) {
            u16x4 o;
#pragma unroll
            for (int r = 0; r < 4; ++r) o[r] = f2bf(ot[f][r] * inv);
            *(u16x4*)&ap[f * 16 + g * 4] = o;
        }
    }
#undef ATT_STAGE
}

extern "C" void kernel_launch(void* const* d_in, const int* in_sizes, int n_in,
                              void* d_out, int out_size, void* d_ws, size_t ws_size,
                              hipStream_t stream) {
    const float* x = (const float*)d_in[0];
    const float* wq = (const float*)d_in[2];
    const float* wk = (const float*)d_in[3];
    const float* wv = (const float*)d_in[4];
    const float* wproj = (const float*)d_in[5];
    const float* bproj = (const float*)d_in[6];
    float* out = (float*)d_out;

    char* ws = (char*)d_ws;
    unsigned short* xb     = (unsigned short*)(ws);               // 8 MB [4096][1024]
    unsigned short* WqkvT  = (unsigned short*)(ws + (8u << 20));  // 6 MB [3072][1024]
    unsigned short* WprojT = (unsigned short*)(ws + (14u << 20)); // 2 MB [1024][1024]
    unsigned short* Qb     = (unsigned short*)(ws + (16u << 20)); // 8 MB [32][2048][64]
    unsigned short* Kb     = (unsigned short*)(ws + (24u << 20)); // 8 MB [32][2048][64]
    unsigned short* Vt     = (unsigned short*)(ws + (32u << 20)); // 8 MB [32][64][2048]
    unsigned short* att    = xb;  // reuse: xb dead after gemm1   // 8 MB [4096][1024]

    k_cast<<<2048, 256, 0, stream>>>(x, xb);
    k_transw3<<<dim3(16, 1, 48), 256, 0, stream>>>(wq, wk, wv, WqkvT);
    k_transw<<<dim3(16, 16, 1), 256, 0, stream>>>(wproj, WprojT, 1024);
    k_gemm<1, 24><<<768, 256, 0, stream>>>(xb, WqkvT, 1024, nullptr, nullptr, Qb, Kb, Vt);
    k_attn<<<dim3(8, 32), 512, 0, stream>>>(Qb, Kb, Vt, att);
    k_gemm<3, 8><<<256, 256, 0, stream>>>(att, WprojT, 1024, out, bproj, nullptr, nullptr, nullptr);
}

// Round 5
// 147.813 us; speedup vs baseline: 1.0800x; 1.0800x over previous
//
#include <hip/hip_runtime.h>
#include <math.h>

typedef float f32x4 __attribute__((ext_vector_type(4)));
typedef __bf16 bf16x8 __attribute__((ext_vector_type(8)));
typedef unsigned short u16x8 __attribute__((ext_vector_type(8)));
typedef unsigned short u16x4 __attribute__((ext_vector_type(4)));

#define DEV static __device__ __forceinline__

DEV unsigned short f2bf(float f) {
    unsigned int u = __builtin_bit_cast(unsigned int, f);
    u += 0x7fffu + ((u >> 16) & 1u);   // RNE
    return (unsigned short)(u >> 16);
}

// async global->LDS, 16B per lane; LDS dest is wave-uniform base + lane*16
#define GLD16(gp, lp) __builtin_amdgcn_global_load_lds( \
    (__attribute__((address_space(1))) void*)(gp),      \
    (__attribute__((address_space(3))) void*)(lp), 16, 0, 0)

// counted-vmcnt barrier: raw s_barrier (no drain), waiting only until <=N VMEM
// ops remain outstanding. vmcnt completion is in-order, so "<=N outstanding"
// guarantees everything older than the N newest has landed.
#define WAITBAR(N) asm volatile("s_waitcnt vmcnt(" #N ")\n\ts_barrier" ::: "memory")
#define BARRIER()  asm volatile("s_barrier" ::: "memory")

// ---------------------------------------------------------------- cast x -> bf16
__global__ __launch_bounds__(256) void k_cast(const float* __restrict__ x,
                                              unsigned short* __restrict__ xb) {
    int i = blockIdx.x * 256 + threadIdx.x;
    const float4* p = (const float4*)(x + (size_t)i * 8);
    float4 a = p[0], b = p[1];
    u16x8 o;
    o[0] = f2bf(a.x); o[1] = f2bf(a.y); o[2] = f2bf(a.z); o[3] = f2bf(a.w);
    o[4] = f2bf(b.x); o[5] = f2bf(b.y); o[6] = f2bf(b.z); o[7] = f2bf(b.w);
    *(u16x8*)(xb + (size_t)i * 8) = o;
}

// ---------------- fused transpose+cast of wq,wk,wv: f32 [16 slices][1024][64]
// -> bf16 WqkvT rows [wsel*1024 + slice*64 + d][c]  (leading dim 1024)
__global__ __launch_bounds__(256) void k_transw3(const float* __restrict__ wq,
                                                 const float* __restrict__ wk,
                                                 const float* __restrict__ wv,
                                                 unsigned short* __restrict__ dst) {
    __shared__ unsigned short t[64][68];
    int z = blockIdx.z;          // 0..47
    int wsel = z >> 4, zz = z & 15;
    const float* src = (wsel == 0 ? wq : wsel == 1 ? wk : wv) + (size_t)zz * 65536;
    int r0 = blockIdx.x * 64;
    int tid = threadIdx.x;
#pragma unroll
    for (int it = 0; it < 4; ++it) {
        int r = (tid >> 4) + it * 16;
        int c4 = (tid & 15) * 4;
        float4 v = *(const float4*)&src[(size_t)(r0 + r) * 64 + c4];
        t[c4 + 0][r] = f2bf(v.x);
        t[c4 + 1][r] = f2bf(v.y);
        t[c4 + 2][r] = f2bf(v.z);
        t[c4 + 3][r] = f2bf(v.w);
    }
    __syncthreads();
#pragma unroll
    for (int it = 0; it < 4; ++it) {
        int c = (tid >> 4) + it * 16;
        int r4 = (tid & 15) * 4;
        u16x4 o;
        o[0] = t[c][r4 + 0]; o[1] = t[c][r4 + 1];
        o[2] = t[c][r4 + 2]; o[3] = t[c][r4 + 3];
        int row = wsel * 1024 + zz * 64 + c;
        *(u16x4*)&dst[(size_t)row * 1024 + r0 + r4] = o;
    }
}

// ------------------------------------------- transpose+cast f32 [R][C] -> bf16 [C][R]
__global__ __launch_bounds__(256) void k_transw(const float* __restrict__ src,
                                                unsigned short* __restrict__ dst,
                                                int Cdim) {
    __shared__ unsigned short t[64][68];
    int r0 = blockIdx.x * 64, c0 = blockIdx.y * 64;
    int tid = threadIdx.x;
#pragma unroll
    for (int it = 0; it < 4; ++it) {
        int r = (tid >> 4) + it * 16;
        int c4 = (tid & 15) * 4;
        float4 v = *(const float4*)&src[(size_t)(r0 + r) * Cdim + c0 + c4];
        t[c4 + 0][r] = f2bf(v.x);
        t[c4 + 1][r] = f2bf(v.y);
        t[c4 + 2][r] = f2bf(v.z);
        t[c4 + 3][r] = f2bf(v.w);
    }
    __syncthreads();
#pragma unroll
    for (int it = 0; it < 4; ++it) {
        int c = (tid >> 4) + it * 16;
        int r4 = (tid & 15) * 4;
        u16x4 o;
        o[0] = t[c][r4 + 0]; o[1] = t[c][r4 + 1];
        o[2] = t[c][r4 + 2]; o[3] = t[c][r4 + 3];
        *(u16x4*)&dst[(size_t)(c0 + c) * 1024 + r0 + r4] = o;
    }
}

// ---------------------------------------------------------------- GEMM  C = A * Bt^T
// 128x128 tile, BK=64, 4 waves. Counted-vmcnt double-buffered pipeline:
//   stage(t+1) -> vmcnt(8)+barrier (tile t landed, t+1 stays in flight)
//   -> compute(t) -> barrier (buf free for restage).
// Next tile's loads span the whole compute phase + both barriers.
// XCD supertile swizzle: per-XCD chunk = SUPM bm x SUPN bn (working set fits L2).
template <int STAGE, int NB, int SUPM, int SUPN>
__global__ __launch_bounds__(256) void k_gemm(const unsigned short* __restrict__ A,
                                              const unsigned short* __restrict__ Bt,
                                              int Kd,
                                              float* __restrict__ outF,
                                              const float* __restrict__ bias,
                                              unsigned short* __restrict__ Qb,
                                              unsigned short* __restrict__ Kb,
                                              unsigned short* __restrict__ Vt) {
    __shared__ unsigned short As[2][128 * 64] __attribute__((aligned(16)));
    __shared__ unsigned short Bs[2][128 * 64] __attribute__((aligned(16)));
    const int tid = threadIdx.x, l = tid & 63, w = tid >> 6;
    constexpr int BN_CH = NB / SUPN;   // bn chunks (x SUPM-chunks of bm == 8 XCDs)
    const int orig = blockIdx.x;
    const int xcd = orig & 7, sdx = orig >> 3;
    const int bm = (xcd / BN_CH) * SUPM + (sdx % SUPM);
    const int bn = (xcd % BN_CH) * SUPN + (sdx / SUPM);
    const int wr = w >> 1, wc = w & 1;
    const int g = l >> 4, q = l & 15;
    f32x4 acc[4][4] = {};
    const unsigned short* gA = A + (size_t)(bm * 128 + w * 8 + (l >> 3)) * Kd + (l & 7) * 8;
    const unsigned short* gB = Bt + (size_t)(bn * 128 + w * 8 + (l >> 3)) * Kd + (l & 7) * 8;

#define GSTAGE(buf, k0) do {                                                  \
        _Pragma("unroll")                                                     \
        for (int it = 0; it < 4; ++it) {                                      \
            GLD16(gA + (size_t)(it * 32) * Kd + (k0), &As[buf][(it * 32 + w * 8) * 64]); \
            GLD16(gB + (size_t)(it * 32) * Kd + (k0), &Bs[buf][(it * 32 + w * 8) * 64]); \
        }                                                                     \
    } while (0)

    const int nt = Kd >> 6;
    GSTAGE(0, 0);
    int cur = 0;
    for (int t = 0; t < nt; ++t) {
        if (t + 1 < nt) {
            GSTAGE(cur ^ 1, (t + 1) << 6);  // 8 more loads in flight
            WAITBAR(8);                      // tile t landed; t+1 still flying
        } else {
            WAITBAR(0);                      // last tile: drain
        }
#pragma unroll
        for (int ks = 0; ks < 2; ++ks) {
            bf16x8 af[4], bfr[4];
#pragma unroll
            for (int mi = 0; mi < 4; ++mi)
                af[mi] = *(const bf16x8*)&As[cur][(wr * 64 + mi * 16 + q) * 64 + ks * 32 + g * 8];
#pragma unroll
            for (int ni = 0; ni < 4; ++ni)
                bfr[ni] = *(const bf16x8*)&Bs[cur][(wc * 64 + ni * 16 + q) * 64 + ks * 32 + g * 8];
#pragma unroll
            for (int mi = 0; mi < 4; ++mi)
#pragma unroll
                for (int ni = 0; ni < 4; ++ni)
                    acc[mi][ni] = __builtin_amdgcn_mfma_f32_16x16x32_bf16(
                        af[mi], bfr[ni], acc[mi][ni], 0, 0, 0);
        }
        BARRIER();   // all waves done reading buf[cur] -> restage next iter
        cur ^= 1;
    }
#undef GSTAGE
#pragma unroll
    for (int mi = 0; mi < 4; ++mi)
#pragma unroll
        for (int ni = 0; ni < 4; ++ni)
#pragma unroll
            for (int r = 0; r < 4; ++r) {
                float c = acc[mi][ni][r];
                int m = bm * 128 + wr * 64 + mi * 16 + g * 4 + r;
                int n = bn * 128 + wc * 64 + ni * 16 + q;
                if (STAGE == 1) {
                    int b = m >> 11, t = m & 2047;
                    int proj = n >> 10, rr = n & 1023, h = rr >> 6, d = rr & 63;
                    int bh = b * 16 + h;
                    if (proj == 0)
                        Qb[((size_t)bh * 2048 + t) * 64 + d] = f2bf(c * 0.18033688011112042f);
                    else if (proj == 1)
                        Kb[((size_t)bh * 2048 + t) * 64 + d] = f2bf(c);
                    else
                        Vt[((size_t)bh * 64 + d) * 2048 + t] = f2bf(c);
                } else {
                    outF[(size_t)m * 1024 + n] = c + bias[n];
                }
            }
}

// ---------------------------------------------------------------- flash attention
// Cooperative: 8 waves/block, each wave owns 16 q-rows of a 128-row q-tile.
// K and V tiles (64x64 bf16) staged in LDS via global_load_lds, double-buffered,
// counted-vmcnt pipeline (2 loads/wave/tile -> vmcnt(2)). XOR pre-swizzle on the
// GLOBAL source (LDS stays linear). Causal balance: block processes q-tile pair
// (qt, 15-qt) -> exactly 34 KV-tile iterations; grid 8x32 = 256 blocks.
__global__ __launch_bounds__(512) void k_attn(const unsigned short* __restrict__ Qb,
                                              const unsigned short* __restrict__ Kb,
                                              const unsigned short* __restrict__ Vt,
                                              unsigned short* __restrict__ att) {
    __shared__ unsigned short Ks[2][4096] __attribute__((aligned(16)));  // [buf][64r][64]
    __shared__ unsigned short Vs[2][4096] __attribute__((aligned(16)));  // [buf][64d][64]
    __shared__ unsigned short P[8][16][72];  // per-wave P staging [q][kv], padded
    const int tid = threadIdx.x, l = tid & 63, w = tid >> 6;
    const int pj = blockIdx.x, bh = blockIdx.y;
    const int b = bh >> 4, h = bh & 15;
    const int ql = l & 15, g = l >> 4;
    const unsigned short* Qp = Qb + (size_t)bh * 2048 * 64;
    const unsigned short* Kp = Kb + (size_t)bh * 2048 * 64;
    const unsigned short* Vp = Vt + (size_t)bh * 64 * 2048;

    const int srow = w * 8 + (l >> 3);
    const int schk = (l & 7) ^ (l >> 3);
    const unsigned short* gK0 = Kp + (size_t)srow * 64 + schk * 8;
    const unsigned short* gV0 = Vp + (size_t)srow * 2048 + schk * 8;

#define ATT_STAGE(buf, kvb) do {                                   \
        GLD16(gK0 + (size_t)(kvb) * 64, &Ks[buf][w * 512]);        \
        GLD16(gV0 + (kvb), &Vs[buf][w * 512]);                     \
    } while (0)

    for (int ph = 0; ph < 2; ++ph) {
        const int qt = ph ? (15 - pj) : pj;
        const int q0w = qt * 128 + w * 16;
        const int qg = q0w + ql;
        const int nkv = 2 * qt + 2;
        const int kbd = 2 * qt + (w >> 2);  // this wave's diagonal tile index

        bf16x8 qf0 = *(const bf16x8*)(Qp + (size_t)qg * 64 + g * 8);
        bf16x8 qf1 = *(const bf16x8*)(Qp + (size_t)qg * 64 + 32 + g * 8);
        f32x4 ot[4] = {};
        float mrun = -1e30f, lrun = 0.f;

        ATT_STAGE(0, 0);
        int cur = 0;

        for (int kb = 0; kb < nkv; ++kb) {
            if (kb + 1 < nkv) {
                ATT_STAGE(cur ^ 1, (kb + 1) * 64);  // 2 more loads in flight
                WAITBAR(2);                          // tile kb landed; kb+1 flying
            } else {
                WAITBAR(0);
            }
            if (kb <= kbd) {
                const unsigned short* Kt = &Ks[cur][0];
                const unsigned short* Vtl = &Vs[cur][0];
                f32x4 st[4] = {};
                bf16x8 kf0[4], kf1[4];
#pragma unroll
                for (int f = 0; f < 4; ++f) {
                    int rk = f * 16 + ql, sw = rk & 7;
                    kf0[f] = *(const bf16x8*)&Kt[rk * 64 + ((g ^ sw) * 8)];
                    kf1[f] = *(const bf16x8*)&Kt[rk * 64 + (((g + 4) ^ sw) * 8)];
                }
                __builtin_amdgcn_s_setprio(1);
#pragma unroll
                for (int f = 0; f < 4; ++f) {
                    st[f] = __builtin_amdgcn_mfma_f32_16x16x32_bf16(kf0[f], qf0, st[f], 0, 0, 0);
                    st[f] = __builtin_amdgcn_mfma_f32_16x16x32_bf16(kf1[f], qf1, st[f], 0, 0, 0);
                }
                __builtin_amdgcn_s_setprio(0);
                if (kb == kbd) {  // diagonal tile: causal mask
                    const int kvb = kb * 64;
#pragma unroll
                    for (int f = 0; f < 4; ++f)
#pragma unroll
                        for (int r = 0; r < 4; ++r)
                            if (kvb + f * 16 + g * 4 + r > qg) st[f][r] = -1e30f;
                }
                float pmax = -1e30f;
#pragma unroll
                for (int f = 0; f < 4; ++f)
#pragma unroll
                    for (int r = 0; r < 4; ++r) pmax = fmaxf(pmax, st[f][r]);
                pmax = fmaxf(pmax, __shfl_xor(pmax, 16));
                pmax = fmaxf(pmax, __shfl_xor(pmax, 32));
                float mnew = fmaxf(mrun, pmax);
                float corr = __builtin_amdgcn_exp2f(mrun - mnew);
                float psum = 0.f;
#pragma unroll
                for (int f = 0; f < 4; ++f) {
                    u16x4 pk;
#pragma unroll
                    for (int r = 0; r < 4; ++r) {
                        float p = __builtin_amdgcn_exp2f(st[f][r] - mnew);
                        psum += p;
                        pk[r] = f2bf(p);
                    }
                    *(u16x4*)&P[w][ql][f * 16 + g * 4] = pk;  // b64 write
                }
                psum += __shfl_xor(psum, 16);
                psum += __shfl_xor(psum, 32);
                lrun = lrun * corr + psum;
#pragma unroll
                for (int f = 0; f < 4; ++f) ot[f] *= corr;
                mrun = mnew;
                // wave-internal cross-lane LDS visibility
                asm volatile("s_waitcnt lgkmcnt(0)" ::: "memory");
#pragma unroll
                for (int dc = 0; dc < 2; ++dc) {
                    bf16x8 pf = *(const bf16x8*)&P[w][ql][dc * 32 + g * 8];  // b128 read
                    __builtin_amdgcn_s_setprio(1);
#pragma unroll
                    for (int f = 0; f < 4; ++f) {
                        int rv = f * 16 + ql, sw = rv & 7;
                        bf16x8 vf = *(const bf16x8*)&Vtl[rv * 64 + (((dc * 4 + g) ^ sw) * 8)];
                        ot[f] = __builtin_amdgcn_mfma_f32_16x16x32_bf16(vf, pf, ot[f], 0, 0, 0);
                    }
                    __builtin_amdgcn_s_setprio(0);
                }
            }
            BARRIER();   // all waves done with buf[cur] -> restage next iter
            cur ^= 1;
        }
        float inv = 1.f / lrun;
        unsigned short* ap = att + ((size_t)(b * 2048 + qg)) * 1024 + h * 64;
#pragma unroll
        for (int f = 0; f < 4; ++f) {
            u16x4 o;
#pragma unroll
            for (int r = 0; r < 4; ++r) o[r] = f2bf(ot[f][r] * inv);
            *(u16x4*)&ap[f * 16 + g * 4] = o;
        }
    }
#undef ATT_STAGE
}

extern "C" void kernel_launch(void* const* d_in, const int* in_sizes, int n_in,
                              void* d_out, int out_size, void* d_ws, size_t ws_size,
                              hipStream_t stream) {
    const float* x = (const float*)d_in[0];
    const float* wq = (const float*)d_in[2];
    const float* wk = (const float*)d_in[3];
    const float* wv = (const float*)d_in[4];
    const float* wproj = (const float*)d_in[5];
    const float* bproj = (const float*)d_in[6];
    float* out = (float*)d_out;

    char* ws = (char*)d_ws;
    unsigned short* xb     = (unsigned short*)(ws);               // 8 MB [4096][1024]
    unsigned short* WqkvT  = (unsigned short*)(ws + (8u << 20));  // 6 MB [3072][1024]
    unsigned short* WprojT = (unsigned short*)(ws + (14u << 20)); // 2 MB [1024][1024]
    unsigned short* Qb     = (unsigned short*)(ws + (16u << 20)); // 8 MB [32][2048][64]
    unsigned short* Kb     = (unsigned short*)(ws + (24u << 20)); // 8 MB [32][2048][64]
    unsigned short* Vt     = (unsigned short*)(ws + (32u << 20)); // 8 MB [32][64][2048]
    unsigned short* att    = xb;  // reuse: xb dead after gemm1   // 8 MB [4096][1024]

    k_cast<<<2048, 256, 0, stream>>>(x, xb);
    k_transw3<<<dim3(16, 1, 48), 256, 0, stream>>>(wq, wk, wv, WqkvT);
    k_transw<<<dim3(16, 16, 1), 256, 0, stream>>>(wproj, WprojT, 1024);
    // QKV: 768 wgs; per-XCD supertile 8bm x 12bn (WS ~5MB)
    k_gemm<1, 24, 8, 12><<<768, 256, 0, stream>>>(xb, WqkvT, 1024, nullptr, nullptr, Qb, Kb, Vt);
    k_attn<<<dim3(8, 32), 512, 0, stream>>>(Qb, Kb, Vt, att);
    // proj: 256 wgs; per-XCD supertile 8bm x 4bn (WS ~3MB, L2-resident)
    k_gemm<3, 8, 8, 4><<<256, 256, 0, stream>>>(att, WprojT, 1024, out, bproj, nullptr, nullptr, nullptr);
}